// Round 2
// baseline (320.995 us; speedup 1.0000x reference)
//
#include <hip/hip_runtime.h>
#include <stdint.h>

#define BN 4096
#define DD 128
#define EPSF 1e-6f
#define MARGINF 1.0f
#define RT 64
#define JT 64
#define CHUNK 512

__device__ __forceinline__ unsigned int ord_f32(float f) {
    unsigned int u = __float_as_uint(f);
    return (u & 0x80000000u) ? ~u : (u | 0x80000000u);
}

// --- per-row sum and sum-of-squares ---
__global__ void k_rowstats(const float* __restrict__ e, float* __restrict__ sq,
                           float* __restrict__ s) {
    int wid = threadIdx.x >> 6;
    int lane = threadIdx.x & 63;
    int row = blockIdx.x * 4 + wid;
    float2 v = ((const float2*)(e + (size_t)row * DD))[lane];
    float ss = v.x + v.y;
    float qq = v.x * v.x + v.y * v.y;
    #pragma unroll
    for (int off = 32; off > 0; off >>= 1) {
        ss += __shfl_down(ss, off);
        qq += __shfl_down(qq, off);
    }
    if (lane == 0) { sq[row] = qq; s[row] = ss; }
}

// --- init workspace (ws is poisoned 0xAA before every launch) ---
__global__ void k_init(unsigned long long* __restrict__ pk,
                       unsigned long long* __restrict__ nk,
                       float* __restrict__ acc) {
    int t = blockIdx.x * 256 + threadIdx.x;
    if (t < BN) { pk[t] = 0ULL; nk[t] = ~0ULL; }
    if (t < 2) acc[t] = 0.0f;
}

// --- inverse permutation: tidx[j] = c  =>  inv[c] = j ---
__global__ void k_inv(const int* __restrict__ tidx, int* __restrict__ inv) {
    int j = blockIdx.x * 256 + threadIdx.x;
    inv[tidx[j]] = j;
}

// --- tiled d^2 + masked argmax/argmin selection, iterating mask-column space c ---
// mask[i][c] pairs with embedding row j = inv[c]; masks read fully coalesced.
__global__ __launch_bounds__(256, 2)
void k_select(const float* __restrict__ e,
              const int* __restrict__ pos, const int* __restrict__ neg,
              const float* __restrict__ sq, const float* __restrict__ s,
              const int* __restrict__ inv,
              unsigned long long* __restrict__ pkey,
              unsigned long long* __restrict__ nkey) {
    __shared__ float Al[DD][RT];     // 32 KB, transposed [k][row]
    __shared__ float Bl[DD][JT];     // 32 KB, transposed [k][col]; reused as reduce scratch
    __shared__ float sqi[RT], si[RT];
    __shared__ float sqj[CHUNK], sj[CHUNK];
    __shared__ int   jv[CHUNK];

    const int tid = threadIdx.x;
    const int tx = tid & 15, ty = tid >> 4;
    const int i0 = blockIdx.x * RT;
    const int c0 = blockIdx.y * CHUNK;

    // chunk-level j-side info (j = inv[c])
    for (int t = tid; t < CHUNK; t += 256) {
        int j = inv[c0 + t];
        jv[t] = j;
        sqj[t] = sq[j];
        sj[t] = s[j];
    }

    // stage A transposed (contiguous i-rows)
    for (int it = 0; it < 8; ++it) {
        int id = it * 256 + tid;
        int grp = id >> 2, kk = id & 3;
        int row = grp & (RT - 1);
        int k4 = ((grp >> 6) << 2) + kk;
        float4 v = ((const float4*)(e + (size_t)(i0 + row) * DD))[k4];
        Al[k4 * 4 + 0][row] = v.x; Al[k4 * 4 + 1][row] = v.y;
        Al[k4 * 4 + 2][row] = v.z; Al[k4 * 4 + 3][row] = v.w;
    }
    if (tid < RT) { sqi[tid] = sq[i0 + tid]; si[tid] = s[i0 + tid]; }

    float bpv[4], bnv[4];
    int bpi[4], bni[4];
    #pragma unroll
    for (int r = 0; r < 4; r++) {
        bpv[r] = -3.4e38f; bnv[r] = 3.4e38f;
        bpi[r] = 0x7FFFFFFF; bni[r] = 0x7FFFFFFF;
    }
    const int* prow[4];
    const int* nrow[4];
    #pragma unroll
    for (int r = 0; r < 4; r++) {
        size_t i = (size_t)(i0 + ty * 4 + r);
        prow[r] = pos + i * BN;
        nrow[r] = neg + i * BN;
    }

    for (int jt = 0; jt < CHUNK / JT; jt++) {
        __syncthreads();   // previous tile's compute done; also makes jv/Al visible on first iter
        // stage B transposed: embedding rows jv[jt*JT + rr] (row-granular gather)
        for (int it = 0; it < 8; ++it) {
            int id = it * 256 + tid;
            int grp = id >> 2, kk = id & 3;
            int rr = grp & (JT - 1);
            int k4 = ((grp >> 6) << 2) + kk;
            int jrow = jv[jt * JT + rr];
            float4 v = ((const float4*)(e + (size_t)jrow * DD))[k4];
            Bl[k4 * 4 + 0][rr] = v.x; Bl[k4 * 4 + 1][rr] = v.y;
            Bl[k4 * 4 + 2][rr] = v.z; Bl[k4 * 4 + 3][rr] = v.w;
        }
        __syncthreads();

        float acc[4][4] = {};
        #pragma unroll 8
        for (int k = 0; k < DD; k++) {
            float4 a4 = *(const float4*)&Al[k][ty * 4];
            float4 b4 = *(const float4*)&Bl[k][tx * 4];
            float av[4] = {a4.x, a4.y, a4.z, a4.w};
            float bv[4] = {b4.x, b4.y, b4.z, b4.w};
            #pragma unroll
            for (int r = 0; r < 4; r++)
                #pragma unroll
                for (int c = 0; c < 4; c++)
                    acc[r][c] = fmaf(av[r], bv[c], acc[r][c]);
        }

        const int cbase = c0 + jt * JT;   // mask column base for this tile
        #pragma unroll
        for (int r = 0; r < 4; r++) {
            // coalesced 16-B mask loads; nonzero test works for int32 0/1 AND f32 0.0/1.0
            int4 pm = *(const int4*)(prow[r] + cbase + tx * 4);
            int4 nm = *(const int4*)(nrow[r] + cbase + tx * 4);
            int pmv[4] = {pm.x, pm.y, pm.z, pm.w};
            int nmv[4] = {nm.x, nm.y, nm.z, nm.w};
            float sqiv = sqi[ty * 4 + r], siv = si[ty * 4 + r];
            #pragma unroll
            for (int cc = 0; cc < 4; cc++) {
                int jl = tx * 4 + cc;
                float d2 = sqiv + sqj[jt * JT + jl] - 2.0f * acc[r][cc]
                         + 2.0f * EPSF * (siv - sj[jt * JT + jl])
                         + (float)DD * EPSF * EPSF;
                int j = jv[jt * JT + jl];
                if (pmv[cc] != 0) {
                    if (d2 > bpv[r] || (d2 == bpv[r] && j < bpi[r])) { bpv[r] = d2; bpi[r] = j; }
                }
                if (nmv[cc] != 0) {
                    if (d2 < bnv[r] || (d2 == bnv[r] && j < bni[r])) { bnv[r] = d2; bni[r] = j; }
                }
            }
        }
    }

    // cross-tx merge per row via LDS scratch (aliases Bl)
    __syncthreads();
    float* spv = &Bl[0][0];
    int*   spi = (int*)(spv + 1024);
    float* snv = (float*)(spi + 1024);
    int*   sni = (int*)(snv + 1024);
    #pragma unroll
    for (int r = 0; r < 4; r++) {
        int row = ty * 4 + r;
        spv[row * 16 + tx] = bpv[r]; spi[row * 16 + tx] = bpi[r];
        snv[row * 16 + tx] = bnv[r]; sni[row * 16 + tx] = bni[r];
    }
    __syncthreads();
    if (tid < RT) {
        float bv = -3.4e38f, nv = 3.4e38f;
        int bi = 0x7FFFFFFF, ni = 0x7FFFFFFF;
        for (int t = 0; t < 16; t++) {
            float v = spv[tid * 16 + t]; int ix = spi[tid * 16 + t];
            if (ix != 0x7FFFFFFF && (v > bv || (v == bv && ix < bi))) { bv = v; bi = ix; }
            v = snv[tid * 16 + t]; ix = sni[tid * 16 + t];
            if (ix != 0x7FFFFFFF && (v < nv || (v == nv && ix < ni))) { nv = v; ni = ix; }
        }
        if (bi != 0x7FFFFFFF) {
            unsigned long long key = ((unsigned long long)ord_f32(bv) << 32)
                                   | (unsigned long long)(0xFFFFFFFFu - (unsigned)bi);
            atomicMax(&pkey[i0 + tid], key);
        }
        if (ni != 0x7FFFFFFF) {
            unsigned long long key = ((unsigned long long)ord_f32(nv) << 32)
                                   | (unsigned long long)(unsigned)ni;
            atomicMin(&nkey[i0 + tid], key);
        }
    }
}

// --- per-row triplet loss, wave per row ---
__global__ void k_loss(const float* __restrict__ e,
                       const unsigned long long* __restrict__ pkey,
                       const unsigned long long* __restrict__ nkey,
                       float* __restrict__ acc) {
    int wid = threadIdx.x >> 6, lane = threadIdx.x & 63;
    int row = blockIdx.x * 4 + wid;
    unsigned long long pk = pkey[row], nk = nkey[row];
    if (pk == 0ULL || nk == ~0ULL) return;  // invalid row: weight 0
    int pi = (int)(0xFFFFFFFFu - (unsigned)(pk & 0xFFFFFFFFu));
    int ni = (int)(unsigned)(nk & 0xFFFFFFFFu);
    float2 av = ((const float2*)(e + (size_t)row * DD))[lane];
    float2 pv = ((const float2*)(e + (size_t)pi * DD))[lane];
    float2 nv = ((const float2*)(e + (size_t)ni * DD))[lane];
    float dx, dy;
    dx = av.x - pv.x + EPSF; dy = av.y - pv.y + EPSF;
    float ap2 = dx * dx + dy * dy;
    dx = av.x - nv.x + EPSF; dy = av.y - nv.y + EPSF;
    float an2 = dx * dx + dy * dy;
    dx = pv.x - nv.x + EPSF; dy = pv.y - nv.y + EPSF;
    float pn2 = dx * dx + dy * dy;
    #pragma unroll
    for (int off = 32; off > 0; off >>= 1) {
        ap2 += __shfl_down(ap2, off);
        an2 += __shfl_down(an2, off);
        pn2 += __shfl_down(pn2, off);
    }
    if (lane == 0) {
        float ap = sqrtf(ap2), an = sqrtf(an2), pn = sqrtf(pn2);
        float loss = fmaxf(ap - fminf(an, pn) + MARGINF, 0.0f);
        atomicAdd(&acc[0], loss);
        atomicAdd(&acc[1], 1.0f);
    }
}

// --- finalize scalar ---
__global__ void k_final(const float* __restrict__ acc, float* __restrict__ out) {
    out[0] = acc[0] / fmaxf(acc[1], 1.0f);
}

extern "C" void kernel_launch(void* const* d_in, const int* in_sizes, int n_in,
                              void* d_out, int out_size, void* d_ws, size_t ws_size,
                              hipStream_t stream) {
    const float* e    = (const float*)d_in[0];
    const int*   tidx = (const int*)d_in[1];
    const int*   pos  = (const int*)d_in[2];   // 4-byte mask words (int32 0/1 or f32 0.0/1.0)
    const int*   neg  = (const int*)d_in[3];
    float* out = (float*)d_out;

    unsigned long long* pkey = (unsigned long long*)d_ws;
    unsigned long long* nkey = pkey + BN;
    float* sq  = (float*)(nkey + BN);
    float* s   = sq + BN;
    float* acc = s + BN;       // 2 floats
    int*   inv = (int*)(acc + 2);

    k_init<<<BN / 256, 256, 0, stream>>>(pkey, nkey, acc);
    k_inv<<<BN / 256, 256, 0, stream>>>(tidx, inv);
    k_rowstats<<<BN / 4, 256, 0, stream>>>(e, sq, s);
    dim3 grid(BN / RT, BN / CHUNK);
    k_select<<<grid, 256, 0, stream>>>(e, pos, neg, sq, s, inv, pkey, nkey);
    k_loss<<<BN / 4, 256, 0, stream>>>(e, pkey, nkey, acc);
    k_final<<<1, 1, 0, stream>>>(acc, out);
}

// Round 3
// 224.340 us; speedup vs baseline: 1.4308x; 1.4308x over previous
//
#include <hip/hip_runtime.h>
#include <stdint.h>

#define BN 4096
#define DD 128
#define EPSF 1e-6f
#define MARGINF 1.0f
#define TM 128     // i-tile rows
#define TN 128     // j-tile cols
#define KC 64      // k-chunk
#define CHUNK 256  // j-columns per block (2 j-tiles)

typedef unsigned long long ull;

__device__ __forceinline__ unsigned int ord_f32(float f) {
    unsigned int u = __float_as_uint(f);
    return (u & 0x80000000u) ? ~u : (u | 0x80000000u);
}

// --- prep: row stats + inverse permutation + key init (fused) ---
__global__ void k_prep(const float* __restrict__ e, const int* __restrict__ tidx,
                       float* __restrict__ sq, float* __restrict__ s,
                       int* __restrict__ inv,
                       ull* __restrict__ pk, ull* __restrict__ nk) {
    int wid = threadIdx.x >> 6;
    int lane = threadIdx.x & 63;
    int row = blockIdx.x * 4 + wid;
    float2 v = ((const float2*)(e + (size_t)row * DD))[lane];
    float ss = v.x + v.y;
    float qq = v.x * v.x + v.y * v.y;
    #pragma unroll
    for (int off = 32; off > 0; off >>= 1) {
        ss += __shfl_down(ss, off);
        qq += __shfl_down(qq, off);
    }
    if (lane == 0) {
        sq[row] = qq; s[row] = ss;
        inv[tidx[row]] = row;
        pk[row] = 0ULL; nk[row] = ~0ULL;
    }
}

// --- tiled d^2 + masked argmax/argmin, 128x128 tile, 8x8 microtile ---
// iterate mask-column space c; j = inv[c]; masks fully coalesced.
__global__ __launch_bounds__(256, 2)
void k_select(const float* __restrict__ e,
              const int* __restrict__ pos, const int* __restrict__ neg,
              const float* __restrict__ sq, const float* __restrict__ s,
              const int* __restrict__ inv,
              ull* __restrict__ pkey, ull* __restrict__ nkey) {
    __shared__ float Al[KC][TM];    // 32 KB, k-major
    __shared__ float Bl[KC][TN];    // 32 KB, k-major; reused as merge scratch
    __shared__ float ri[TM];        // sq[i] + 2eps*s[i]
    __shared__ float rj[CHUNK];     // sq[j] - 2eps*s[j]
    __shared__ int   jvs[CHUNK];    // j = inv[c]

    const int tid = threadIdx.x;
    const int tx = tid & 15, ty = tid >> 4;
    const int i0 = blockIdx.x * TM;
    const int c0 = blockIdx.y * CHUNK;

    for (int t = tid; t < CHUNK; t += 256) {
        int j = inv[c0 + t];
        jvs[t] = j;
        rj[t] = sq[j] - 2.0f * EPSF * s[j];
    }
    if (tid < TM) ri[tid] = sq[i0 + tid] + 2.0f * EPSF * s[i0 + tid];

    float bpv[8], bnv[8]; int bpi[8], bni[8];
    #pragma unroll
    for (int r = 0; r < 8; r++) {
        bpv[r] = -3.4e38f; bnv[r] = 3.4e38f;
        bpi[r] = 0x7FFFFFFF; bni[r] = 0x7FFFFFFF;
    }

    for (int jt = 0; jt < CHUNK / TN; jt++) {
        float acc[8][8];
        #pragma unroll
        for (int r = 0; r < 8; r++)
            #pragma unroll
            for (int c = 0; c < 8; c++) acc[r][c] = 0.0f;

        for (int kc = 0; kc < DD / KC; kc++) {
            __syncthreads();   // prev compute done before overwriting tiles
            // stage A chunk (transposed): 128 rows x 16 float4, 8 per thread
            for (int it = 0; it < 8; ++it) {
                int id = it * 256 + tid;
                int grp = id >> 2, kk = id & 3;
                int row = grp & (TM - 1);
                int kq = ((grp >> 7) << 2) + kk;      // 0..15
                float4 v = ((const float4*)(e + (size_t)(i0 + row) * DD + kc * KC))[kq];
                int k = kq * 4;
                Al[k + 0][row] = v.x; Al[k + 1][row] = v.y;
                Al[k + 2][row] = v.z; Al[k + 3][row] = v.w;
            }
            // stage B chunk (transposed, gathered rows)
            for (int it = 0; it < 8; ++it) {
                int id = it * 256 + tid;
                int grp = id >> 2, kk = id & 3;
                int rr = grp & (TN - 1);
                int kq = ((grp >> 7) << 2) + kk;
                int jrow = jvs[jt * TN + rr];
                float4 v = ((const float4*)(e + (size_t)jrow * DD + kc * KC))[kq];
                int k = kq * 4;
                Bl[k + 0][rr] = v.x; Bl[k + 1][rr] = v.y;
                Bl[k + 2][rr] = v.z; Bl[k + 3][rr] = v.w;
            }
            __syncthreads();

            #pragma unroll 2
            for (int k = 0; k < KC; k++) {
                float4 a0 = *(const float4*)&Al[k][ty * 8];
                float4 a1 = *(const float4*)&Al[k][ty * 8 + 4];
                float4 b0 = *(const float4*)&Bl[k][tx * 8];
                float4 b1 = *(const float4*)&Bl[k][tx * 8 + 4];
                float av[8] = {a0.x, a0.y, a0.z, a0.w, a1.x, a1.y, a1.z, a1.w};
                float bv[8] = {b0.x, b0.y, b0.z, b0.w, b1.x, b1.y, b1.z, b1.w};
                #pragma unroll
                for (int r = 0; r < 8; r++)
                    #pragma unroll
                    for (int c = 0; c < 8; c++)
                        acc[r][c] = fmaf(av[r], bv[c], acc[r][c]);
            }
        }

        // epilogue: masks + selection for this j-tile
        const int cbase = c0 + jt * TN;
        float rjv[8]; int jjv[8];
        #pragma unroll
        for (int c = 0; c < 8; c++) {
            int jl = jt * TN + tx * 8 + c;
            rjv[c] = rj[jl];
            jjv[c] = jvs[jl];
        }
        #pragma unroll
        for (int r = 0; r < 8; r++) {
            int irow = ty * 8 + r;
            const int* pr = pos + (size_t)(i0 + irow) * BN + cbase + tx * 8;
            const int* nr = neg + (size_t)(i0 + irow) * BN + cbase + tx * 8;
            int4 pm0 = ((const int4*)pr)[0], pm1 = ((const int4*)pr)[1];
            int4 nm0 = ((const int4*)nr)[0], nm1 = ((const int4*)nr)[1];
            int pmv[8] = {pm0.x, pm0.y, pm0.z, pm0.w, pm1.x, pm1.y, pm1.z, pm1.w};
            int nmv[8] = {nm0.x, nm0.y, nm0.z, nm0.w, nm1.x, nm1.y, nm1.z, nm1.w};
            float riv = ri[irow];
            #pragma unroll
            for (int c = 0; c < 8; c++) {
                float d2 = riv + rjv[c] - 2.0f * acc[r][c] + (float)DD * EPSF * EPSF;
                int j = jjv[c];
                if (pmv[c] != 0) {
                    if (d2 > bpv[r] || (d2 == bpv[r] && j < bpi[r])) { bpv[r] = d2; bpi[r] = j; }
                }
                if (nmv[c] != 0) {
                    if (d2 < bnv[r] || (d2 == bnv[r] && j < bni[r])) { bnv[r] = d2; bni[r] = j; }
                }
            }
        }
    }

    // cross-tx merge via LDS scratch (aliases Bl: 8192 floats, need exactly 4x2048)
    __syncthreads();
    float* spv = &Bl[0][0];
    int*   spi = (int*)(spv + 2048);
    float* snv = (float*)(spi + 2048);
    int*   sni = (int*)(snv + 2048);
    #pragma unroll
    for (int r = 0; r < 8; r++) {
        int row = ty * 8 + r;
        spv[row * 16 + tx] = bpv[r]; spi[row * 16 + tx] = bpi[r];
        snv[row * 16 + tx] = bnv[r]; sni[row * 16 + tx] = bni[r];
    }
    __syncthreads();
    if (tid < TM) {
        float bv = -3.4e38f, nv = 3.4e38f;
        int bi = 0x7FFFFFFF, ni = 0x7FFFFFFF;
        for (int t = 0; t < 16; t++) {
            float v = spv[tid * 16 + t]; int ix = spi[tid * 16 + t];
            if (ix != 0x7FFFFFFF && (v > bv || (v == bv && ix < bi))) { bv = v; bi = ix; }
            v = snv[tid * 16 + t]; ix = sni[tid * 16 + t];
            if (ix != 0x7FFFFFFF && (v < nv || (v == nv && ix < ni))) { nv = v; ni = ix; }
        }
        if (bi != 0x7FFFFFFF) {
            ull key = ((ull)ord_f32(bv) << 32) | (ull)(0xFFFFFFFFu - (unsigned)bi);
            atomicMax(&pkey[i0 + tid], key);
        }
        if (ni != 0x7FFFFFFF) {
            ull key = ((ull)ord_f32(nv) << 32) | (ull)(unsigned)ni;
            atomicMin(&nkey[i0 + tid], key);
        }
    }
}

// --- per-row triplet loss: thread per row, block partials (no hot atomics) ---
__global__ void k_loss(const float* __restrict__ e,
                       const ull* __restrict__ pkey, const ull* __restrict__ nkey,
                       float* __restrict__ partials) {
    int tid = threadIdx.x;
    int row = blockIdx.x * 256 + tid;
    ull pk = pkey[row], nk = nkey[row];
    float loss = 0.0f, w = 0.0f;
    if (pk != 0ULL && nk != ~0ULL) {
        int pi = (int)(0xFFFFFFFFu - (unsigned)(pk & 0xFFFFFFFFu));
        int ni = (int)(unsigned)(nk & 0xFFFFFFFFu);
        const float4* a4 = (const float4*)(e + (size_t)row * DD);
        const float4* p4 = (const float4*)(e + (size_t)pi * DD);
        const float4* n4 = (const float4*)(e + (size_t)ni * DD);
        float ap2 = 0.0f, an2 = 0.0f, pn2 = 0.0f;
        #pragma unroll 8
        for (int k = 0; k < DD / 4; k++) {
            float4 a = a4[k], p = p4[k], n = n4[k];
            float d;
            d = a.x - p.x + EPSF; ap2 = fmaf(d, d, ap2);
            d = a.y - p.y + EPSF; ap2 = fmaf(d, d, ap2);
            d = a.z - p.z + EPSF; ap2 = fmaf(d, d, ap2);
            d = a.w - p.w + EPSF; ap2 = fmaf(d, d, ap2);
            d = a.x - n.x + EPSF; an2 = fmaf(d, d, an2);
            d = a.y - n.y + EPSF; an2 = fmaf(d, d, an2);
            d = a.z - n.z + EPSF; an2 = fmaf(d, d, an2);
            d = a.w - n.w + EPSF; an2 = fmaf(d, d, an2);
            d = p.x - n.x + EPSF; pn2 = fmaf(d, d, pn2);
            d = p.y - n.y + EPSF; pn2 = fmaf(d, d, pn2);
            d = p.z - n.z + EPSF; pn2 = fmaf(d, d, pn2);
            d = p.w - n.w + EPSF; pn2 = fmaf(d, d, pn2);
        }
        float ap = sqrtf(ap2), an = sqrtf(an2), pn = sqrtf(pn2);
        loss = fmaxf(ap - fminf(an, pn) + MARGINF, 0.0f);
        w = 1.0f;
    }
    // block reduction: wave shuffle -> LDS -> thread 0
    __shared__ float sl[4], sw[4];
    int wid = tid >> 6, lane = tid & 63;
    #pragma unroll
    for (int off = 32; off > 0; off >>= 1) {
        loss += __shfl_down(loss, off);
        w    += __shfl_down(w, off);
    }
    if (lane == 0) { sl[wid] = loss; sw[wid] = w; }
    __syncthreads();
    if (tid == 0) {
        float L = sl[0] + sl[1] + sl[2] + sl[3];
        float W = sw[0] + sw[1] + sw[2] + sw[3];
        partials[blockIdx.x * 2 + 0] = L;
        partials[blockIdx.x * 2 + 1] = W;
    }
}

// --- finalize scalar ---
__global__ void k_final(const float* __restrict__ partials, float* __restrict__ out) {
    float L = 0.0f, W = 0.0f;
    for (int b = 0; b < BN / 256; b++) { L += partials[2 * b]; W += partials[2 * b + 1]; }
    out[0] = L / fmaxf(W, 1.0f);
}

extern "C" void kernel_launch(void* const* d_in, const int* in_sizes, int n_in,
                              void* d_out, int out_size, void* d_ws, size_t ws_size,
                              hipStream_t stream) {
    const float* e    = (const float*)d_in[0];
    const int*   tidx = (const int*)d_in[1];
    const int*   pos  = (const int*)d_in[2];   // 4-byte mask words (int32 0/1 or f32 0.0/1.0)
    const int*   neg  = (const int*)d_in[3];
    float* out = (float*)d_out;

    ull*   pkey = (ull*)d_ws;
    ull*   nkey = pkey + BN;
    float* sq   = (float*)(nkey + BN);
    float* s    = sq + BN;
    int*   inv  = (int*)(s + BN);
    float* partials = (float*)(inv + BN);   // 2 * (BN/256) floats

    k_prep<<<BN / 4, 256, 0, stream>>>(e, tidx, sq, s, inv, pkey, nkey);
    dim3 grid(BN / TM, BN / CHUNK);
    k_select<<<grid, 256, 0, stream>>>(e, pos, neg, sq, s, inv, pkey, nkey);
    k_loss<<<BN / 256, 256, 0, stream>>>(e, pkey, nkey, partials);
    k_final<<<1, 1, 0, stream>>>(partials, out);
}

// Round 4
// 209.183 us; speedup vs baseline: 1.5345x; 1.0725x over previous
//
#include <hip/hip_runtime.h>
#include <stdint.h>

#define BN 4096
#define DD 128
#define EPSF 1e-6f
#define MARGINF 1.0f
#define TM 128
#define TN 128
#define KC 64

typedef unsigned long long ull;
typedef short short8 __attribute__((ext_vector_type(8)));
typedef float f32x4 __attribute__((ext_vector_type(4)));

__device__ __forceinline__ unsigned int ord_f32(float f) {
    unsigned int u = __float_as_uint(f);
    return (u & 0x80000000u) ? ~u : (u | 0x80000000u);
}
__device__ __forceinline__ unsigned short bf16_rne(float x) {
    unsigned int u = __float_as_uint(x);
    return (unsigned short)((u + 0x7FFFu + ((u >> 16) & 1u)) >> 16);
}

// --- prep: row stats + inv perm + key init + bf16 hi/lo split of e ---
__global__ void k_prep(const float* __restrict__ e, const int* __restrict__ tidx,
                       float* __restrict__ sq, float* __restrict__ s,
                       int* __restrict__ inv, ull* __restrict__ pk, ull* __restrict__ nk,
                       unsigned int* __restrict__ ehi, unsigned int* __restrict__ elo) {
    int w = threadIdx.x >> 6, lane = threadIdx.x & 63;
    int row = blockIdx.x * 4 + w;
    float2 v = ((const float2*)(e + (size_t)row * DD))[lane];
    // hi/lo bf16 split
    unsigned short hx = bf16_rne(v.x), hy = bf16_rne(v.y);
    float rx = v.x - __uint_as_float((unsigned int)hx << 16);
    float ry = v.y - __uint_as_float((unsigned int)hy << 16);
    unsigned short lx = bf16_rne(rx), ly = bf16_rne(ry);
    ehi[row * 64 + lane] = (unsigned int)hx | ((unsigned int)hy << 16);
    elo[row * 64 + lane] = (unsigned int)lx | ((unsigned int)ly << 16);
    float ss = v.x + v.y;
    float qq = v.x * v.x + v.y * v.y;
    #pragma unroll
    for (int off = 32; off > 0; off >>= 1) {
        ss += __shfl_down(ss, off);
        qq += __shfl_down(qq, off);
    }
    if (lane == 0) {
        sq[row] = qq; s[row] = ss;
        inv[tidx[row]] = row;
        pk[row] = 0ULL; nk[row] = ~0ULL;
    }
}

// --- compress int32/f32 masks to bitmaps (pure HBM-bound, coalesced) ---
__global__ void k_bits(const int* __restrict__ pos, const int* __restrict__ neg,
                       ull* __restrict__ pb, ull* __restrict__ nb) {
    int row = blockIdx.x;
    int w = threadIdx.x >> 6, lane = threadIdx.x & 63;
    const int* pr = pos + (size_t)row * BN;
    const int* nr = neg + (size_t)row * BN;
    #pragma unroll 4
    for (int g = 0; g < 16; g++) {
        int col = g * 256 + w * 64 + lane;
        ull b = __ballot(pr[col] != 0);
        if (lane == 0) pb[row * 64 + g * 4 + w] = b;
        b = __ballot(nr[col] != 0);
        if (lane == 0) nb[row * 64 + g * 4 + w] = b;
    }
}

// --- MFMA split-bf16 d^2 + masked argmax/argmin over a 128x128 tile ---
__global__ __launch_bounds__(256, 2)
void k_select(const unsigned short* __restrict__ ehi, const unsigned short* __restrict__ elo,
              const float* __restrict__ sq, const float* __restrict__ s,
              const int* __restrict__ inv,
              const ull* __restrict__ pbits, const ull* __restrict__ nbits,
              ull* __restrict__ pkey, ull* __restrict__ nkey) {
    // 4 staging buffers: [128 rows][64+8 pad ushorts] = 18432 B each; D/scratch alias
    __shared__ __align__(16) char smem[73728];
    __shared__ int   jvs[TN];
    __shared__ float ri[TM], rj[TN];
    __shared__ ull   pbl[256], nbl[256];

    unsigned short* Ah = (unsigned short*)smem;
    unsigned short* Alo = Ah + 9216;
    unsigned short* Bh = Ah + 18432;
    unsigned short* Blo = Ah + 27648;
    float* Dl = (float*)smem;                 // [128][132] floats

    const int tid = threadIdx.x;
    const int i0 = blockIdx.x * TM;
    const int c0 = blockIdx.y * TN;

    // small arrays + bitmask tile (4 KB)
    if (tid < TN) {
        int j = inv[c0 + tid];
        jvs[tid] = j;
        rj[tid] = sq[j] - 2.0f * EPSF * s[j];
        ri[tid] = sq[i0 + tid] + 2.0f * EPSF * s[i0 + tid];
    }
    {
        int irow = tid >> 1, half = tid & 1;
        size_t bidx = (size_t)(i0 + irow) * 64 + (c0 >> 6) + half;
        pbl[tid] = pbits[bidx];
        nbl[tid] = nbits[bidx];
    }

    const int lane = tid & 63, w = tid >> 6;
    const int lrow = lane & 15, quad = lane >> 4;

    f32x4 acc[2][8];
    #pragma unroll
    for (int rt = 0; rt < 2; rt++)
        #pragma unroll
        for (int ct = 0; ct < 8; ct++)
            acc[rt][ct] = (f32x4){0.f, 0.f, 0.f, 0.f};

    for (int kc = 0; kc < DD / KC; kc++) {
        __syncthreads();   // prior frag reads done (1st iter: jvs visible)
        // stage: 4 passes x 4 buffers; row = p*32 + t/8, seg = t%8 (16B each)
        {
            int rr0 = tid >> 3, seg = tid & 7;
            #pragma unroll
            for (int p = 0; p < 4; p++) {
                int rr = p * 32 + rr0;
                int ar = i0 + rr;
                int jr = jvs[rr];
                int4 va = ((const int4*)(ehi + (size_t)ar * DD))[kc * 8 + seg];
                int4 vb = ((const int4*)(elo + (size_t)ar * DD))[kc * 8 + seg];
                *(int4*)(Ah + rr * 72 + seg * 8) = va;
                *(int4*)(Alo + rr * 72 + seg * 8) = vb;
                va = ((const int4*)(ehi + (size_t)jr * DD))[kc * 8 + seg];
                vb = ((const int4*)(elo + (size_t)jr * DD))[kc * 8 + seg];
                *(int4*)(Bh + rr * 72 + seg * 8) = va;
                *(int4*)(Blo + rr * 72 + seg * 8) = vb;
            }
        }
        __syncthreads();

        #pragma unroll
        for (int ks = 0; ks < 2; ks++) {
            const int kof = ks * 32 + quad * 8;
            short8 ahi[2], alo2[2];
            #pragma unroll
            for (int rt = 0; rt < 2; rt++) {
                const unsigned short* ap = Ah + (w * 32 + rt * 16 + lrow) * 72 + kof;
                const unsigned short* lp = Alo + (w * 32 + rt * 16 + lrow) * 72 + kof;
                ahi[rt] = *(const short8*)ap;
                alo2[rt] = *(const short8*)lp;
            }
            #pragma unroll
            for (int ct = 0; ct < 8; ct++) {
                const unsigned short* bp = Bh + (ct * 16 + lrow) * 72 + kof;
                const unsigned short* blp = Blo + (ct * 16 + lrow) * 72 + kof;
                short8 bhi = *(const short8*)bp;
                short8 blo = *(const short8*)blp;
                #pragma unroll
                for (int rt = 0; rt < 2; rt++) {
                    acc[rt][ct] = __builtin_amdgcn_mfma_f32_16x16x32_bf16(ahi[rt], bhi, acc[rt][ct], 0, 0, 0);
                    acc[rt][ct] = __builtin_amdgcn_mfma_f32_16x16x32_bf16(ahi[rt], blo, acc[rt][ct], 0, 0, 0);
                    acc[rt][ct] = __builtin_amdgcn_mfma_f32_16x16x32_bf16(alo2[rt], bhi, acc[rt][ct], 0, 0, 0);
                }
            }
        }
    }

    // write D to LDS (C-layout: col=lane&15, row=quad*4+reg)
    __syncthreads();
    #pragma unroll
    for (int rt = 0; rt < 2; rt++)
        #pragma unroll
        for (int ct = 0; ct < 8; ct++) {
            int rbase = w * 32 + rt * 16 + quad * 4;
            int col = ct * 16 + lrow;
            #pragma unroll
            for (int t = 0; t < 4; t++)
                Dl[(rbase + t) * 132 + col] = acc[rt][ct][t];
        }
    __syncthreads();

    // selection epilogue (8 rows x 8 cols per thread)
    const int tx = tid & 15, ty = tid >> 4;
    float bpv[8], bnv[8]; int bpi[8], bni[8];
    #pragma unroll
    for (int r = 0; r < 8; r++) {
        bpv[r] = -3.4e38f; bnv[r] = 3.4e38f;
        bpi[r] = 0x7FFFFFFF; bni[r] = 0x7FFFFFFF;
    }
    const int shift = (tx & 7) * 8;
    #pragma unroll
    for (int r = 0; r < 8; r++) {
        int irow = ty * 8 + r;
        float4 d0 = *(const float4*)&Dl[irow * 132 + tx * 8];
        float4 d1 = *(const float4*)&Dl[irow * 132 + tx * 8 + 4];
        float dot[8] = {d0.x, d0.y, d0.z, d0.w, d1.x, d1.y, d1.z, d1.w};
        unsigned int pb = (unsigned int)((pbl[irow * 2 + (tx >> 3)] >> shift) & 0xFFu);
        unsigned int nb = (unsigned int)((nbl[irow * 2 + (tx >> 3)] >> shift) & 0xFFu);
        float riv = ri[irow];
        #pragma unroll
        for (int c = 0; c < 8; c++) {
            int jl = tx * 8 + c;
            float d2 = riv + rj[jl] - 2.0f * dot[c] + (float)DD * EPSF * EPSF;
            int j = jvs[jl];
            if ((pb >> c) & 1u) {
                if (d2 > bpv[r] || (d2 == bpv[r] && j < bpi[r])) { bpv[r] = d2; bpi[r] = j; }
            }
            if ((nb >> c) & 1u) {
                if (d2 < bnv[r] || (d2 == bnv[r] && j < bni[r])) { bnv[r] = d2; bni[r] = j; }
            }
        }
    }

    // cross-tx merge (scratch aliases smem; all D reads done)
    __syncthreads();
    float* spv = (float*)smem;
    int*   spi = (int*)(spv + 2048);
    float* snv = (float*)(spi + 2048);
    int*   sni = (int*)(snv + 2048);
    #pragma unroll
    for (int r = 0; r < 8; r++) {
        int row = ty * 8 + r;
        spv[row * 16 + tx] = bpv[r]; spi[row * 16 + tx] = bpi[r];
        snv[row * 16 + tx] = bnv[r]; sni[row * 16 + tx] = bni[r];
    }
    __syncthreads();
    if (tid < TM) {
        float bv = -3.4e38f, nv = 3.4e38f;
        int bi = 0x7FFFFFFF, ni = 0x7FFFFFFF;
        for (int t = 0; t < 16; t++) {
            float v = spv[tid * 16 + t]; int ix = spi[tid * 16 + t];
            if (ix != 0x7FFFFFFF && (v > bv || (v == bv && ix < bi))) { bv = v; bi = ix; }
            v = snv[tid * 16 + t]; ix = sni[tid * 16 + t];
            if (ix != 0x7FFFFFFF && (v < nv || (v == nv && ix < ni))) { nv = v; ni = ix; }
        }
        if (bi != 0x7FFFFFFF) {
            ull key = ((ull)ord_f32(bv) << 32) | (ull)(0xFFFFFFFFu - (unsigned)bi);
            atomicMax(&pkey[i0 + tid], key);
        }
        if (ni != 0x7FFFFFFF) {
            ull key = ((ull)ord_f32(nv) << 32) | (ull)(unsigned)ni;
            atomicMin(&nkey[i0 + tid], key);
        }
    }
}

// --- per-row triplet loss: wave per row (coalesced), block partials ---
__global__ void k_loss(const float* __restrict__ e,
                       const ull* __restrict__ pkey, const ull* __restrict__ nkey,
                       float* __restrict__ partials) {
    int w = threadIdx.x >> 6, lane = threadIdx.x & 63;
    int row = blockIdx.x * 4 + w;
    ull pk = pkey[row], nk = nkey[row];
    float loss = 0.0f, wt = 0.0f;
    if (pk != 0ULL && nk != ~0ULL) {
        int pi = (int)(0xFFFFFFFFu - (unsigned)(pk & 0xFFFFFFFFu));
        int ni = (int)(unsigned)(nk & 0xFFFFFFFFu);
        float2 av = ((const float2*)(e + (size_t)row * DD))[lane];
        float2 pv = ((const float2*)(e + (size_t)pi * DD))[lane];
        float2 nv = ((const float2*)(e + (size_t)ni * DD))[lane];
        float dx, dy;
        dx = av.x - pv.x + EPSF; dy = av.y - pv.y + EPSF;
        float ap2 = dx * dx + dy * dy;
        dx = av.x - nv.x + EPSF; dy = av.y - nv.y + EPSF;
        float an2 = dx * dx + dy * dy;
        dx = pv.x - nv.x + EPSF; dy = pv.y - nv.y + EPSF;
        float pn2 = dx * dx + dy * dy;
        #pragma unroll
        for (int off = 32; off > 0; off >>= 1) {
            ap2 += __shfl_down(ap2, off);
            an2 += __shfl_down(an2, off);
            pn2 += __shfl_down(pn2, off);
        }
        if (lane == 0) {
            float ap = sqrtf(ap2), an = sqrtf(an2), pn = sqrtf(pn2);
            loss = fmaxf(ap - fminf(an, pn) + MARGINF, 0.0f);
            wt = 1.0f;
        }
    }
    __shared__ float sl[4], sw[4];
    if (lane == 0) { sl[w] = loss; sw[w] = wt; }
    __syncthreads();
    if (threadIdx.x == 0) {
        partials[blockIdx.x * 2 + 0] = sl[0] + sl[1] + sl[2] + sl[3];
        partials[blockIdx.x * 2 + 1] = sw[0] + sw[1] + sw[2] + sw[3];
    }
}

// --- finalize ---
__global__ void k_final(const float* __restrict__ partials, float* __restrict__ out) {
    int tid = threadIdx.x;
    float L = 0.0f, W = 0.0f;
    for (int i = 0; i < 4; i++) {
        int idx = tid + i * 256;
        L += partials[idx * 2];
        W += partials[idx * 2 + 1];
    }
    #pragma unroll
    for (int off = 32; off > 0; off >>= 1) {
        L += __shfl_down(L, off);
        W += __shfl_down(W, off);
    }
    __shared__ float sl[4], sw[4];
    int w = tid >> 6, lane = tid & 63;
    if (lane == 0) { sl[w] = L; sw[w] = W; }
    __syncthreads();
    if (tid == 0) {
        float Lt = sl[0] + sl[1] + sl[2] + sl[3];
        float Wt = sw[0] + sw[1] + sw[2] + sw[3];
        out[0] = Lt / fmaxf(Wt, 1.0f);
    }
}

extern "C" void kernel_launch(void* const* d_in, const int* in_sizes, int n_in,
                              void* d_out, int out_size, void* d_ws, size_t ws_size,
                              hipStream_t stream) {
    const float* e    = (const float*)d_in[0];
    const int*   tidx = (const int*)d_in[1];
    const int*   pos  = (const int*)d_in[2];
    const int*   neg  = (const int*)d_in[3];
    float* out = (float*)d_out;

    ull* pkey  = (ull*)d_ws;                  // 4096
    ull* nkey  = pkey + BN;                   // 4096
    ull* pbits = nkey + BN;                   // 4096*64
    ull* nbits = pbits + BN * 64;             // 4096*64
    float* sq  = (float*)(nbits + BN * 64);
    float* s   = sq + BN;
    int* inv   = (int*)(s + BN);
    float* partials = (float*)(inv + BN);     // 2048
    unsigned int* ehi = (unsigned int*)(partials + 2048);  // 4096*64 uints
    unsigned int* elo = ehi + BN * 64;

    k_prep<<<BN / 4, 256, 0, stream>>>(e, tidx, sq, s, inv, pkey, nkey, ehi, elo);
    k_bits<<<BN, 256, 0, stream>>>(pos, neg, pbits, nbits);
    dim3 grid(BN / TM, BN / TN);
    k_select<<<grid, 256, 0, stream>>>((const unsigned short*)ehi, (const unsigned short*)elo,
                                       sq, s, inv, pbits, nbits, pkey, nkey);
    k_loss<<<BN / 4, 256, 0, stream>>>(e, pkey, nkey, partials);
    k_final<<<1, 256, 0, stream>>>(partials, out);
}